// Round 5
// baseline (1651.413 us; speedup 1.0000x reference)
//
#include <hip/hip_runtime.h>
#include <hip/hip_bf16.h>
#include <math.h>

// ---- problem constants ----
#define D_  768
#define T_  1024
#define B_  2
#define H_  12
#define HD_ 64
#define L_  8
#define F_  3072
#define V_  1024
#define M_  (B_ * T_)   // 2048 rows of activations

typedef __bf16 bf16_t;
typedef __bf16 bf16x8 __attribute__((ext_vector_type(8)));
typedef float  f32x4  __attribute__((ext_vector_type(4)));

// async 16B global->LDS (direct DMA, lane i lands at lds_base + i*16)
__device__ __forceinline__ void ld_g2l16(const bf16_t* g, bf16_t* l)
{
    __builtin_amdgcn_global_load_lds(
        (const __attribute__((address_space(1))) void*)g,
        (__attribute__((address_space(3))) void*)l,
        16, 0, 0);
}

// ---------------- embed: x = tok_emb[ids] + pos_emb (all f32) ----------------
__global__ __launch_bounds__(256) void embed_kernel(
    const int* __restrict__ ids, const float* __restrict__ tok,
    const float* __restrict__ pos, float* __restrict__ x)
{
    const int row = blockIdx.x;          // b*T + t
    const int t   = row & (T_ - 1);
    const int id  = ids[row];
    const int c   = threadIdx.x;
#pragma unroll
    for (int i = 0; i < 3; ++i) {
        const int d = c + i * 256;
        x[(size_t)row * D_ + d] = tok[(size_t)id * D_ + d] + pos[(size_t)t * D_ + d];
    }
}

// -------- weight transpose+convert, all layers: f32 [L][K][N] -> bf16 [L][N][K] -----
__global__ __launch_bounds__(256) void wtrans_kernel(
    const float* __restrict__ in, bf16_t* __restrict__ out, int K, int N)
{
    __shared__ float tile[32][33];
    const float* inl = in + (size_t)blockIdx.z * K * N;
    bf16_t* outl = out + (size_t)blockIdx.z * N * K;
    const int n0 = blockIdx.x * 32, k0 = blockIdx.y * 32;
    const int tx = threadIdx.x & 31, ty = threadIdx.x >> 5;   // ty 0..7
#pragma unroll
    for (int i = 0; i < 4; ++i)
        tile[ty + 8 * i][tx] = inl[(size_t)(k0 + ty + 8 * i) * N + n0 + tx];
    __syncthreads();
#pragma unroll
    for (int i = 0; i < 4; ++i) {
        const int n = ty + 8 * i;
        outl[(size_t)(n0 + n) * K + k0 + tx] = (bf16_t)tile[tx][n];
    }
}

// ---------------- straight convert f32 -> bf16 (tok_emb for lm_head) ----------------
__global__ __launch_bounds__(256) void conv_kernel(
    const float* __restrict__ in, bf16_t* __restrict__ out)
{
    const int i = blockIdx.x * 1024 + threadIdx.x * 4;
    const f32x4 v = *(const f32x4*)(in + i);
#pragma unroll
    for (int j = 0; j < 4; ++j) out[i + j] = (bf16_t)v[j];
}

// ---------------- layernorm: f32 in -> bf16 out ----------------
__device__ __forceinline__ float block_sum(float v)
{
    __shared__ float sm[4];
#pragma unroll
    for (int off = 32; off; off >>= 1) v += __shfl_down(v, off);
    if ((threadIdx.x & 63) == 0) sm[threadIdx.x >> 6] = v;
    __syncthreads();
    const float r = sm[0] + sm[1] + sm[2] + sm[3];
    __syncthreads();
    return r;
}

__global__ __launch_bounds__(256) void ln_kernel(
    const float* __restrict__ x, const float* __restrict__ w,
    const float* __restrict__ b, bf16_t* __restrict__ out)
{
    const int row = blockIdx.x;
    const float* xr = x + (size_t)row * D_;
    const int t = threadIdx.x;
    const float v0 = xr[t];
    const float v1 = xr[t + 256];
    const float v2 = xr[t + 512];
    const float mu = block_sum(v0 + v1 + v2) * (1.f / D_);
    const float d0 = v0 - mu, d1 = v1 - mu, d2 = v2 - mu;
    const float var = block_sum(d0 * d0 + d1 * d1 + d2 * d2) * (1.f / D_);
    const float rstd = rsqrtf(var + 1e-5f);
    bf16_t* o = out + (size_t)row * D_;
    o[t]       = (bf16_t)(d0 * rstd * w[t]       + b[t]);
    o[t + 256] = (bf16_t)(d1 * rstd * w[t + 256] + b[t + 256]);
    o[t + 512] = (bf16_t)(d2 * rstd * w[t + 512] + b[t + 512]);
}

// ---------------- GEMM (B^T bf16): C[M,N] = act(A[M,K] @ Bt[N,K]^T + bias + res) ----
// BK=32. 4 waves in 2x2 quadrants; wave tile (BM/2)x(BN/2); MT=BM/32, NT=BN/32
// 16x16 MFMA tiles per wave -> MT*NT MFMA + (MT+NT) ds_read_b128 per K-iter.
// Staging: global_load_lds width=16, unpadded LDS (m104/m108: wave-uniform base +
// lane*16). XOR swizzle: 16B chunk of logical index c for row r sits at slot
// c ^ ((r>>1)&3); bank-group (4r+slot)%8 then covers all 8 groups over any 16
// consecutive rows -> 2 lanes/group = free (m136).
// MFMA layouts (m89/m91): A/B frag idx=lane&15, k=quad*8+j; D row=quad*4+reg, col=lane&15.
template<int BM, int BN, bool RES, bool BIAS, bool GELU_, bool OUTF32>
__global__ __launch_bounds__(256) void gemm_bt(
    const bf16_t* __restrict__ A, const bf16_t* __restrict__ Bt,
    const float* __restrict__ bias, const float* __restrict__ res,
    void* __restrict__ Cp, int M, int N, int K)
{
    constexpr int BK = 32;
    constexpr int MT = BM / 32, NT = BN / 32;    // per-wave 16x16 tiles
    constexpr int AR = BM / 64, BR = BN / 64;    // 256-lane staging rounds
    __shared__ bf16_t As[BM * BK];
    __shared__ bf16_t Bs[BN * BK];

    const int t    = threadIdx.x;
    const int wave = t >> 6, lane = t & 63;
    const int lr   = lane & 15, quad = lane >> 4;
    const int bm0  = blockIdx.y * BM, bn0 = blockIdx.x * BN;
    const int wm   = wave >> 1, wn = wave & 1;

    f32x4 acc[MT][NT];
#pragma unroll
    for (int i = 0; i < MT; ++i)
#pragma unroll
        for (int j = 0; j < NT; ++j) { f32x4 z = {0.f, 0.f, 0.f, 0.f}; acc[i][j] = z; }

    // staging source pointers (lane fetches the chunk its swizzled LDS slot holds)
    const bf16_t* asrc[AR];
    const bf16_t* bsrc[BR];
#pragma unroll
    for (int rnd = 0; rnd < AR; ++rnd) {
        const int idx = rnd * 256 + t, row = idx >> 2, slot = idx & 3;
        const int c = slot ^ ((row >> 1) & 3);
        asrc[rnd] = A + (size_t)(bm0 + row) * K + c * 8;
    }
#pragma unroll
    for (int rnd = 0; rnd < BR; ++rnd) {
        const int idx = rnd * 256 + t, row = idx >> 2, slot = idx & 3;
        const int c = slot ^ ((row >> 1) & 3);
        bsrc[rnd] = Bt + (size_t)(bn0 + row) * K + c * 8;
    }

    for (int k0 = 0; k0 < K; k0 += BK) {
        __syncthreads();   // previous iter's LDS reads done
#pragma unroll
        for (int rnd = 0; rnd < AR; ++rnd)
            ld_g2l16(asrc[rnd] + k0, As + (rnd * 256 + wave * 64) * 8);
#pragma unroll
        for (int rnd = 0; rnd < BR; ++rnd)
            ld_g2l16(bsrc[rnd] + k0, Bs + (rnd * 256 + wave * 64) * 8);
        __syncthreads();   // compiler drains vmcnt before barrier -> data ready

        bf16x8 af[MT], bfr[NT];
#pragma unroll
        for (int mt = 0; mt < MT; ++mt) {
            const int row = wm * (BM / 2) + mt * 16 + lr;
            const int slot = quad ^ ((row >> 1) & 3);
            af[mt] = *(const bf16x8*)(As + row * BK + slot * 8);
        }
#pragma unroll
        for (int nt = 0; nt < NT; ++nt) {
            const int row = wn * (BN / 2) + nt * 16 + lr;
            const int slot = quad ^ ((row >> 1) & 3);
            bfr[nt] = *(const bf16x8*)(Bs + row * BK + slot * 8);
        }
#pragma unroll
        for (int mt = 0; mt < MT; ++mt)
#pragma unroll
            for (int nt = 0; nt < NT; ++nt)
                acc[mt][nt] = __builtin_amdgcn_mfma_f32_16x16x32_bf16(af[mt], bfr[nt], acc[mt][nt], 0, 0, 0);
    }

    // epilogue: D row=quad*4+r, col=lane&15
#pragma unroll
    for (int mt = 0; mt < MT; ++mt) {
        const int mbase = bm0 + wm * (BM / 2) + mt * 16 + quad * 4;
#pragma unroll
        for (int nt = 0; nt < NT; ++nt) {
            const int n = bn0 + wn * (BN / 2) + nt * 16 + lr;
            const float bv = BIAS ? bias[n] : 0.f;
#pragma unroll
            for (int r = 0; r < 4; ++r) {
                const int m = mbase + r;
                float v = acc[mt][nt][r] + bv;
                if (RES)   v += res[(size_t)m * N + n];
                if (GELU_) v = 0.5f * v * (1.f + erff(v * 0.70710678118654752f));
                if (OUTF32) ((float*)Cp)[(size_t)m * N + n] = v;
                else        ((bf16_t*)Cp)[(size_t)m * N + n] = (bf16_t)v;
            }
        }
    }
}

// ---------------- flash attention, MFMA (unchanged — passed) ----------
__global__ __launch_bounds__(256) void attn_kernel(
    const bf16_t* __restrict__ qkv, bf16_t* __restrict__ y)
{
    __shared__ bf16_t Ks[64][72];
    __shared__ bf16_t Vt[64][72];
    __shared__ bf16_t Ps[4][16][72];

    const int q0   = blockIdx.x * 64;
    const int bh   = blockIdx.y;
    const int b    = bh / H_;
    const int hh   = bh % H_;
    const int t    = threadIdx.x;
    const int wave = t >> 6;
    const int lane = t & 63;
    const int lr   = lane & 15;
    const int quad = lane >> 4;

    const size_t qg = ((size_t)b * T_ + q0 + wave * 16 + lr) * (3 * D_) + hh * HD_;
    const bf16x8 aQ0 = *(const bf16x8*)(qkv + qg + quad * 8);
    const bf16x8 aQ1 = *(const bf16x8*)(qkv + qg + 32 + quad * 8);

    f32x4 o[4];
#pragma unroll
    for (int i = 0; i < 4; ++i) { f32x4 z = {0.f, 0.f, 0.f, 0.f}; o[i] = z; }
    float mrow[4] = {-1e30f, -1e30f, -1e30f, -1e30f};
    float lrow[4] = {0.f, 0.f, 0.f, 0.f};

    for (int kt = 0; kt <= (int)blockIdx.x; ++kt) {
        const int k_base = kt * 64;
        __syncthreads();

        {
            const int key = t >> 2, dc = (t & 3) * 8;
            const size_t g = ((size_t)b * T_ + k_base + key) * (3 * D_) + D_ + hh * HD_;
            *(bf16x8*)(&Ks[key][dc])      = *(const bf16x8*)(qkv + g + dc);
            *(bf16x8*)(&Ks[key][dc + 32]) = *(const bf16x8*)(qkv + g + dc + 32);
        }
        {
            const int key = lane;
            const size_t g = ((size_t)b * T_ + k_base + key) * (3 * D_) + 2 * D_ + hh * HD_ + wave * 16;
            const bf16x8 v0 = *(const bf16x8*)(qkv + g);
            const bf16x8 v1 = *(const bf16x8*)(qkv + g + 8);
#pragma unroll
            for (int i = 0; i < 8; ++i) {
                Vt[wave * 16 + i][key]     = v0[i];
                Vt[wave * 16 + 8 + i][key] = v1[i];
            }
        }
        __syncthreads();

        f32x4 s[4];
#pragma unroll
        for (int i = 0; i < 4; ++i) { f32x4 z = {0.f, 0.f, 0.f, 0.f}; s[i] = z; }
#pragma unroll
        for (int nt = 0; nt < 4; ++nt) {
            bf16x8 bk0 = *(const bf16x8*)(&Ks[nt * 16 + lr][quad * 8]);
            bf16x8 bk1 = *(const bf16x8*)(&Ks[nt * 16 + lr][32 + quad * 8]);
            s[nt] = __builtin_amdgcn_mfma_f32_16x16x32_bf16(aQ0, bk0, s[nt], 0, 0, 0);
            s[nt] = __builtin_amdgcn_mfma_f32_16x16x32_bf16(aQ1, bk1, s[nt], 0, 0, 0);
        }

#pragma unroll
        for (int r = 0; r < 4; ++r) {
            const int qg_i = q0 + wave * 16 + quad * 4 + r;
            float mx = -1e30f;
#pragma unroll
            for (int nt = 0; nt < 4; ++nt) {
                float sv = s[nt][r] * 0.125f;
                if (k_base + nt * 16 + lr > qg_i) sv = -1e30f;
                s[nt][r] = sv;
                mx = fmaxf(mx, sv);
            }
            mx = fmaxf(mx, __shfl_xor(mx, 1));
            mx = fmaxf(mx, __shfl_xor(mx, 2));
            mx = fmaxf(mx, __shfl_xor(mx, 4));
            mx = fmaxf(mx, __shfl_xor(mx, 8));
            const float mnew = fmaxf(mrow[r], mx);
            float ps = 0.f;
#pragma unroll
            for (int nt = 0; nt < 4; ++nt) {
                const float p = __expf(s[nt][r] - mnew);
                s[nt][r] = p;
                ps += p;
            }
            ps += __shfl_xor(ps, 1);
            ps += __shfl_xor(ps, 2);
            ps += __shfl_xor(ps, 4);
            ps += __shfl_xor(ps, 8);
            const float alpha = __expf(mrow[r] - mnew);
            lrow[r] = lrow[r] * alpha + ps;
            mrow[r] = mnew;
#pragma unroll
            for (int nt = 0; nt < 4; ++nt) o[nt][r] *= alpha;
        }

#pragma unroll
        for (int nt = 0; nt < 4; ++nt)
#pragma unroll
            for (int r = 0; r < 4; ++r)
                Ps[wave][quad * 4 + r][nt * 16 + lr] = (bf16_t)s[nt][r];

        const bf16x8 aP0 = *(const bf16x8*)(&Ps[wave][lr][quad * 8]);
        const bf16x8 aP1 = *(const bf16x8*)(&Ps[wave][lr][32 + quad * 8]);
#pragma unroll
        for (int nt = 0; nt < 4; ++nt) {
            bf16x8 bv0 = *(const bf16x8*)(&Vt[nt * 16 + lr][quad * 8]);
            bf16x8 bv1 = *(const bf16x8*)(&Vt[nt * 16 + lr][32 + quad * 8]);
            o[nt] = __builtin_amdgcn_mfma_f32_16x16x32_bf16(aP0, bv0, o[nt], 0, 0, 0);
            o[nt] = __builtin_amdgcn_mfma_f32_16x16x32_bf16(aP1, bv1, o[nt], 0, 0, 0);
        }
    }

#pragma unroll
    for (int r = 0; r < 4; ++r) {
        const float inv = 1.f / lrow[r];
        const size_t row = (size_t)b * T_ + q0 + wave * 16 + quad * 4 + r;
#pragma unroll
        for (int nt = 0; nt < 4; ++nt)
            y[row * D_ + hh * HD_ + nt * 16 + lr] = (bf16_t)(o[nt][r] * inv);
    }
}

// ---------------- launch ----------------
extern "C" void kernel_launch(void* const* d_in, const int* in_sizes, int n_in,
                              void* d_out, int out_size, void* d_ws, size_t ws_size,
                              hipStream_t stream)
{
    const int*   ids  = (const int*)d_in[0];
    const float* tok  = (const float*)d_in[1];
    const float* pos  = (const float*)d_in[2];
    const float* l1w  = (const float*)d_in[3];
    const float* l1b  = (const float*)d_in[4];
    const float* qkvw = (const float*)d_in[5];
    const float* outw = (const float*)d_in[6];
    const float* l2w  = (const float*)d_in[7];
    const float* l2b  = (const float*)d_in[8];
    const float* w1   = (const float*)d_in[9];
    const float* b1   = (const float*)d_in[10];
    const float* w2   = (const float*)d_in[11];
    const float* b2   = (const float*)d_in[12];
    const float* lnfw = (const float*)d_in[13];
    const float* lnfb = (const float*)d_in[14];

    float*  x     = (float*)d_ws;                       // [2048][768]  f32
    bf16_t* h     = (bf16_t*)(x + (size_t)M_ * D_);     // [2048][768]
    bf16_t* qkv   = h     + (size_t)M_ * D_;            // [2048][2304]
    bf16_t* y     = qkv   + (size_t)M_ * 3 * D_;        // [2048][768]
    bf16_t* mid   = y     + (size_t)M_ * D_;            // [2048][3072]
    bf16_t* tokb  = mid   + (size_t)M_ * F_;            // [1024][768]
    bf16_t* wqkvT = tokb  + (size_t)V_ * D_;            // [L][2304][768]
    bf16_t* woutT = wqkvT + (size_t)L_ * 3 * D_ * D_;   // [L][768][768]
    bf16_t* w1T   = woutT + (size_t)L_ * D_ * D_;       // [L][3072][768]
    bf16_t* w2T   = w1T   + (size_t)L_ * F_ * D_;       // [L][768][3072]

    embed_kernel<<<M_, 256, 0, stream>>>(ids, tok, pos, x);
    conv_kernel<<<(V_ * D_) / 1024, 256, 0, stream>>>(tok, tokb);

    // all-layer weight transposes (4 dispatches)
    wtrans_kernel<<<dim3(3 * D_ / 32, D_ / 32, L_), 256, 0, stream>>>(qkvw, wqkvT, D_, 3 * D_);
    wtrans_kernel<<<dim3(D_ / 32, D_ / 32, L_),     256, 0, stream>>>(outw, woutT, D_, D_);
    wtrans_kernel<<<dim3(F_ / 32, D_ / 32, L_),     256, 0, stream>>>(w1,   w1T,   D_, F_);
    wtrans_kernel<<<dim3(D_ / 32, F_ / 32, L_),     256, 0, stream>>>(w2,   w2T,   F_, D_);

    for (int l = 0; l < L_; ++l) {
        ln_kernel<<<M_, 256, 0, stream>>>(x, l1w + l * D_, l1b + l * D_, h);
        gemm_bt<128, 128, false, false, false, false><<<dim3(3 * D_ / 128, M_ / 128), 256, 0, stream>>>(
            h, wqkvT + (size_t)l * 3 * D_ * D_, nullptr, nullptr, qkv, M_, 3 * D_, D_);
        attn_kernel<<<dim3(T_ / 64, B_ * H_), 256, 0, stream>>>(qkv, y);
        gemm_bt<64, 128, true, false, false, true><<<dim3(D_ / 128, M_ / 64), 256, 0, stream>>>(
            y, woutT + (size_t)l * D_ * D_, nullptr, x, x, M_, D_, D_);
        ln_kernel<<<M_, 256, 0, stream>>>(x, l2w + l * D_, l2b + l * D_, h);
        gemm_bt<128, 128, false, true, true, false><<<dim3(F_ / 128, M_ / 128), 256, 0, stream>>>(
            h, w1T + (size_t)l * F_ * D_, b1 + (size_t)l * F_, nullptr, mid, M_, F_, D_);
        gemm_bt<64, 128, true, true, false, true><<<dim3(D_ / 128, M_ / 64), 256, 0, stream>>>(
            mid, w2T + (size_t)l * D_ * F_, b2 + (size_t)l * D_, x, x, M_, D_, F_);
    }

    ln_kernel<<<M_, 256, 0, stream>>>(x, lnfw, lnfb, h);
    gemm_bt<64, 128, false, false, false, true><<<dim3(V_ / 128, M_ / 64), 256, 0, stream>>>(
        h, tokb, nullptr, nullptr, d_out, M_, V_, D_);
}